// Round 6
// baseline (229.916 us; speedup 1.0000x reference)
//
#include <hip/hip_runtime.h>
#include <math.h>

#define IMG_H 2048
#define IMG_W 2048
#define NB    8
#define BORDER 10
#define REP_THR 0.6f

typedef float f32x4 __attribute__((ext_vector_type(4)));

// Copy-shaped NMS: one thread per float4 of OUTPUT (2^23 threads).
//
// ROUND 6 CHANGE (single variable vs round 5): plain cached stores instead
// of __builtin_nontemporal_store. Evidence: R0 (plain stores) was the
// fastest variant; R1-R5 all used nt stores and all plateaued at 75-85us
// with hbm_gbps ~2.4-2.8 TB/s despite five different structures. The fill
// kernel shows the fast write path is the NORMAL one: 6.7 TB/s via L2
// write-allocate + full-line writeback. nt bypasses L2's write coalescing
// and appears to throttle the store stream; and its claimed benefit
// (keeping L2 for input) is moot -- FETCH=66MB shows input reuse is
// already fully served by L2/L3.
//
// Structure (unchanged from R5): 3 float4 loads (rows y-1,y,y+1) + 6
// scalar halo loads (same cache lines -> L1 hits), ~30 VALU ops, 1 store.
// XCD swizzle: 32768 blocks = 8 XCDs x 4096; image k -> XCD k, so
// vertical halo re-reads stay inside one XCD's 4 MiB L2.
//
// Border: rows [0,10) u [2038,2048) and col-groups 0/511 write zeros with
// no loads. Interior threads need rows y-1..y+1 in [9,2038] -- always in
// bounds, so the hot path has no clamps and no divergence.
__global__ __launch_bounds__(256) void nms_kernel(const float* __restrict__ in,
                                                  float* __restrict__ out) {
    const int orig = blockIdx.x;
    const int swz  = (orig & 7) * 4096 + (orig >> 3);
    const int tid  = (swz << 8) | threadIdx.x;   // 0 .. 2^23-1

    const int gx = tid & 511;           // float4 index within row
    const int y  = (tid >> 9) & 2047;   // row
    const int b  = tid >> 20;           // image

    const int x4 = gx << 2;             // 0..2044

    const size_t img_off = (size_t)b * IMG_H * IMG_W;
    float* optr = out + img_off + (size_t)y * IMG_W + x4;

    // Zero-only threads: row border or column-border float4 groups.
    if (y < BORDER || y >= IMG_H - BORDER || gx == 0 || gx == 511) {
        const f32x4 z = {0.f, 0.f, 0.f, 0.f};
        *(f32x4*)optr = z;
        return;
    }

    const float* base = in + img_off + (size_t)y * IMG_W + x4;
    const float* r0 = base - IMG_W;
    const float* r1 = base;
    const float* r2 = base + IMG_W;

    // Three rows: aligned float4 + left/right scalar halos (L1 hits).
    const f32x4 v0 = *(const f32x4*)r0;
    const f32x4 v1 = *(const f32x4*)r1;
    const f32x4 v2 = *(const f32x4*)r2;
    const float l0 = r0[-1], q0 = r0[4];
    const float l1 = r1[-1], q1 = r1[4];
    const float l2 = r2[-1], q2 = r2[4];

    // Horizontal 3-max per row (clang fuses fmaxf pairs to v_max3_f32).
    f32x4 h0, h1, h2;
    h0[0] = fmaxf(l0,    fmaxf(v0[0], v0[1]));
    h0[1] = fmaxf(v0[0], fmaxf(v0[1], v0[2]));
    h0[2] = fmaxf(v0[1], fmaxf(v0[2], v0[3]));
    h0[3] = fmaxf(v0[2], fmaxf(v0[3], q0));
    h1[0] = fmaxf(l1,    fmaxf(v1[0], v1[1]));
    h1[1] = fmaxf(v1[0], fmaxf(v1[1], v1[2]));
    h1[2] = fmaxf(v1[1], fmaxf(v1[2], v1[3]));
    h1[3] = fmaxf(v1[2], fmaxf(v1[3], q1));
    h2[0] = fmaxf(l2,    fmaxf(v2[0], v2[1]));
    h2[1] = fmaxf(v2[0], fmaxf(v2[1], v2[2]));
    h2[2] = fmaxf(v2[1], fmaxf(v2[2], v2[3]));
    h2[3] = fmaxf(v2[2], fmaxf(v2[3], q2));

    // Vertical 3-max.
    f32x4 m;
    m[0] = fmaxf(h0[0], fmaxf(h1[0], h2[0]));
    m[1] = fmaxf(h0[1], fmaxf(h1[1], h2[1]));
    m[2] = fmaxf(h0[2], fmaxf(h1[2], h2[2]));
    m[3] = fmaxf(h0[3], fmaxf(h1[3], h2[3]));

    // Column border mask (rows already known interior).
    const bool bx0 = (x4 + 0 >= BORDER) && (x4 + 0 < IMG_W - BORDER);
    const bool bx1 = (x4 + 1 >= BORDER) && (x4 + 1 < IMG_W - BORDER);
    const bool bx2 = (x4 + 2 >= BORDER) && (x4 + 2 < IMG_W - BORDER);
    const bool bx3 = (x4 + 3 >= BORDER) && (x4 + 3 < IMG_W - BORDER);

    f32x4 r;
    r[0] = (v1[0] == m[0] && v1[0] >= REP_THR && bx0) ? 1.f : 0.f;
    r[1] = (v1[1] == m[1] && v1[1] >= REP_THR && bx1) ? 1.f : 0.f;
    r[2] = (v1[2] == m[2] && v1[2] >= REP_THR && bx2) ? 1.f : 0.f;
    r[3] = (v1[3] == m[3] && v1[3] >= REP_THR && bx3) ? 1.f : 0.f;

    *(f32x4*)optr = r;
}

extern "C" void kernel_launch(void* const* d_in, const int* in_sizes, int n_in,
                              void* d_out, int out_size, void* d_ws, size_t ws_size,
                              hipStream_t stream) {
    const float* in = (const float*)d_in[0];
    float* out = (float*)d_out;
    const int total_threads = NB * IMG_H * (IMG_W / 4);  // 2^23
    const int block = 256;
    const int grid = total_threads / block;              // 32768
    nms_kernel<<<grid, block, 0, stream>>>(in, out);
}